// Round 4
// baseline (633.184 us; speedup 1.0000x reference)
//
#include <hip/hip_runtime.h>
#include <hip/hip_bf16.h>
#include <stdint.h>
#include <math.h>

// Problem constants (B=2,S=2048 -> T=4096 tokens), D=1024, U=4096, E=8, K=2
#define TTOK 4096
#define DDIM 1024
#define UDIM 4096
#define NEXP 8
#define KSPLIT 2            // split-K chunks for stage_down (K=4096 -> 2x2048)
#define KCH   (UDIM / KSPLIT)
#define NPAIR (TTOK * 2)
#define EPAD 72             // epilogue LDS bounce row stride (shorts)
#define CPAD 32             // counter padding (ints) -> one counter per 128B line
#define RTOK 16             // tokens per router block (256 blocks)

using float4v = __attribute__((ext_vector_type(4))) float;
using short8  = __attribute__((ext_vector_type(8))) short;
using ushort8 = __attribute__((ext_vector_type(8))) unsigned short;
using ushort4v = __attribute__((ext_vector_type(4))) unsigned short;

__device__ __forceinline__ unsigned short f2bf(float f) {
  union { float f; unsigned u; } v; v.f = f;
  unsigned r = v.u + 0x7FFFu + ((v.u >> 16) & 1u);  // RNE
  return (unsigned short)(r >> 16);
}
__device__ __forceinline__ float bf2f(unsigned short u) {
  union { unsigned u; float f; } v; v.u = ((unsigned)u) << 16;
  return v.f;
}
__device__ __forceinline__ void load_lds16(const void* g, void* l) {
  __builtin_amdgcn_global_load_lds(
      (const __attribute__((address_space(1))) unsigned int*)g,
      (__attribute__((address_space(3))) unsigned int*)l, 16, 0, 0);
}
// 8 fp32 -> 8 bf16 (RNE), packed
__device__ __forceinline__ short8 cvt8(const float4v a, const float4v b) {
  union { __hip_bfloat162 h[4]; short8 s; } u;
  u.h[0] = __float22bfloat162_rn(make_float2(a[0], a[1]));
  u.h[1] = __float22bfloat162_rn(make_float2(a[2], a[3]));
  u.h[2] = __float22bfloat162_rn(make_float2(b[0], b[1]));
  u.h[3] = __float22bfloat162_rn(make_float2(b[2], b[3]));
  return u.s;
}
// tanh-form gelu: v * sigmoid(2*0.797885*(v+0.044715 v^3)); NaN-safe at +-inf of exp
__device__ __forceinline__ float gelu_f(float v) {
  float u = v * (0.7978845608f + 0.0356774081f * v * v);
  float ex = __expf(2.0f * u);
  return v * (1.0f - 1.0f / (1.0f + ex));
}

// ---------------- router: block-aggregated counting sort, 16 tokens/block.
// Emits xb (bf16 x), wpair/epair, per-expert gather lists. 8 padded atomics/block. ----------------
__global__ void router_kernel(const float* __restrict__ x,
                              const float* __restrict__ wr,
                              int* __restrict__ counts, int* __restrict__ list,
                              float* __restrict__ wpair, int* __restrict__ epair,
                              unsigned short* __restrict__ xb) {
  __shared__ int sE0[RTOK], sE1[RTOK];
  const int bid = blockIdx.x;
  const int tid = threadIdx.x;
  const int wave = tid >> 6, lane = tid & 63;
#pragma unroll 1
  for (int j = 0; j < RTOK / 4; j++) {           // 4 tokens per wave
    const int slot = wave * (RTOK / 4) + j;
    const int t = bid * RTOK + slot;
    float acc[NEXP];
#pragma unroll
    for (int e = 0; e < NEXP; e++) acc[e] = 0.0f;
    const float* xr = x + (size_t)t * DDIM;
    unsigned short* xbr = xb + (size_t)t * DDIM;
#pragma unroll
    for (int it = 0; it < 4; it++) {
      const int d = it * 256 + lane * 4;
      float4v xv = *(const float4v*)(xr + d);
      ushort4v xo;
#pragma unroll
      for (int c = 0; c < 4; c++) xo[c] = f2bf(xv[c]);
      *(ushort4v*)(xbr + d) = xo;
#pragma unroll
      for (int e = 0; e < NEXP; e++) {
        float4v wv = *(const float4v*)(wr + e * DDIM + d);
        acc[e] += xv[0] * wv[0] + xv[1] * wv[1] + xv[2] * wv[2] + xv[3] * wv[3];
      }
    }
#pragma unroll
    for (int e = 0; e < NEXP; e++) {
#pragma unroll
      for (int off = 32; off > 0; off >>= 1) acc[e] += __shfl_xor(acc[e], off, 64);
    }
    if (lane == 0) {
      int e0 = 0; float l0 = acc[0];
      for (int e = 1; e < NEXP; e++) if (acc[e] > l0) { l0 = acc[e]; e0 = e; }
      int e1 = -1; float l1 = -3.4e38f;
      for (int e = 0; e < NEXP; e++) if (e != e0 && acc[e] > l1) { l1 = acc[e]; e1 = e; }
      float s1 = expf(l1 - l0);
      float inv = 1.0f / (1.0f + s1);
      wpair[2 * t] = inv;          epair[2 * t] = e0;
      wpair[2 * t + 1] = s1 * inv; epair[2 * t + 1] = e1;
      sE0[slot] = e0;  sE1[slot] = e1;
    }
  }
  __syncthreads();
  // 8 threads: per-expert count, one padded atomic, deterministic within-block scatter
  if (tid < NEXP) {
    const int e = tid;
    int cnt = 0;
#pragma unroll
    for (int s = 0; s < RTOK; s++) cnt += (sE0[s] == e) + (sE1[s] == e);
    int r = atomicAdd(&counts[e * CPAD], cnt);
    int* le = list + e * TTOK;
#pragma unroll 1
    for (int s = 0; s < RTOK; s++) {
      const int p = 2 * (bid * RTOK + s);
      if (sE0[s] == e) le[r++] = p;
      if (sE1[s] == e) le[r++] = p + 1;
    }
  }
}

// ======== stage A: h[pair,u] = gelu(x . Wup + bup).
// A (gathered bf16 x) via global_load_lds; B (fp32 w_up) reg-staged: dwordx4 loads
// issued one K-step ahead, cvt8 -> ds_write_b128 into the same LDS layout.
// No weight pre-conversion pass: w_up is fetched exactly once, as fp32. ========
__global__ __launch_bounds__(256, 4) void stage_up_rs(
    const unsigned short* __restrict__ xb, const float* __restrict__ wu,
    const float* __restrict__ bup, const int* __restrict__ counts,
    const int* __restrict__ list, unsigned short* __restrict__ h) {
  const int e = blockIdx.z, mt = blockIdx.y, nt = blockIdx.x;
  const int cnt = counts[e * CPAD];
  if (mt * 128 >= cnt) return;
  const int rem = min(128, cnt - mt * 128);
  const int* lst = list + e * TTOK + mt * 128;

  __shared__ __align__(16) char SM[18432];   // A bf16 8K | B bf16 8K; epilogue bounce 18K
  unsigned short* Sb = (unsigned short*)SM;

  const int tid = threadIdx.x;
  const int wave = tid >> 6, lane = tid & 63;
  const int srow = tid >> 2, cell = tid & 3;          // 4 thr/row: row K-slice = 32 elems

  const int tok0 = lst[min(srow, rem - 1)] >> 1;
  const int tok1 = lst[min(srow + 64, rem - 1)] >> 1;
  const unsigned short* a0 = xb + (size_t)tok0 * DDIM + cell * 8;
  const unsigned short* a1 = xb + (size_t)tok1 * DDIM + cell * 8;
  const float* bw0 = wu + ((size_t)e * UDIM + nt * 128 + srow) * DDIM + cell * 8;
  const float* bw1 = bw0 + (size_t)64 * DDIM;

  const int wm = wave >> 1, wn = wave & 1;
  const int lane15 = lane & 15, quad = lane >> 4;
  const int abyte = (wm * 64 + lane15) * 64 + quad * 16;
  const int bbyte = 8192 + (wn * 64 + lane15) * 64 + quad * 16;

  // 1-deep B prefetch (T14 async-split: issue early, write late)
  float4v p00 = *(const float4v*)(bw0);
  float4v p01 = *(const float4v*)(bw0 + 4);
  float4v p10 = *(const float4v*)(bw1);
  float4v p11 = *(const float4v*)(bw1 + 4);

  float4v acc[4][4];
#pragma unroll
  for (int i = 0; i < 4; i++)
#pragma unroll
    for (int j = 0; j < 4; j++) acc[i][j] = (float4v){0.f, 0.f, 0.f, 0.f};

  for (int k0 = 0; k0 < DDIM; k0 += 32) {
    load_lds16(a0 + k0, SM + tid * 16);
    load_lds16(a1 + k0, SM + 4096 + tid * 16);
    short8 bv0 = cvt8(p00, p01);
    short8 bv1 = cvt8(p10, p11);
    if (k0 + 32 < DDIM) {
      p00 = *(const float4v*)(bw0 + k0 + 32);
      p01 = *(const float4v*)(bw0 + k0 + 36);
      p10 = *(const float4v*)(bw1 + k0 + 32);
      p11 = *(const float4v*)(bw1 + k0 + 36);
    }
    *(short8*)(SM + 8192 + tid * 16) = bv0;   // ds_write_b128, same layout as gload_lds path
    *(short8*)(SM + 12288 + tid * 16) = bv1;
    __syncthreads();
    short8 af[4], bfr[4];
#pragma unroll
    for (int mi = 0; mi < 4; mi++) af[mi] = *(const short8*)(SM + abyte + mi * 1024);
#pragma unroll
    for (int ni = 0; ni < 4; ni++) bfr[ni] = *(const short8*)(SM + bbyte + ni * 1024);
#pragma unroll
    for (int mi = 0; mi < 4; mi++)
#pragma unroll
      for (int ni = 0; ni < 4; ni++)
        acc[mi][ni] = __builtin_amdgcn_mfma_f32_16x16x32_bf16(af[mi], bfr[ni], acc[mi][ni], 0, 0, 0);
    __syncthreads();
  }

  // epilogue: +bias, fast gelu -> bf16, LDS bounce, coalesced 16B stores
  const int ucol0 = nt * 128 + wn * 64;
  float bias[4];
#pragma unroll
  for (int ni = 0; ni < 4; ni++) bias[ni] = bup[e * UDIM + ucol0 + ni * 16 + lane15];
  const int row = tid >> 1, seg = tid & 1;
  const int opair = (row < rem) ? lst[row] : -1;
#pragma unroll
  for (int hh = 0; hh < 2; hh++) {
    if (wn == hh) {
#pragma unroll
      for (int mi = 0; mi < 4; mi++)
#pragma unroll
        for (int r = 0; r < 4; r++) {
          const int rl = wm * 64 + mi * 16 + quad * 4 + r;
#pragma unroll
          for (int ni = 0; ni < 4; ni++)
            Sb[rl * EPAD + ni * 16 + lane15] = f2bf(gelu_f(acc[mi][ni][r] + bias[ni]));
        }
    }
    __syncthreads();
    if (opair >= 0) {
      unsigned short* dst = h + (size_t)opair * UDIM + nt * 128 + hh * 64 + seg * 32;
      const unsigned short* src = Sb + row * EPAD + seg * 32;
#pragma unroll
      for (int c = 0; c < 4; c++) *(ushort8*)(dst + c * 8) = *(const ushort8*)(src + c * 8);
    }
    __syncthreads();
  }
}

// ======== stage B: partial[kc][pair] = h . Wdown (no bias/w). Same reg-staged B (fp32 w_down).
// Grid: x = mt*2+kc (64), y = nt (8): the 8 nt-siblings sharing one gathered A-tile land
// on the SAME XCD (bid%8 = x%8), A fetched once per L2; wd panels are L3-resident. ========
__global__ __launch_bounds__(256, 4) void stage_down_rs(
    const unsigned short* __restrict__ h, const float* __restrict__ wd,
    const int* __restrict__ counts, const int* __restrict__ list,
    unsigned short* __restrict__ part) {
  const int e = blockIdx.z, mt = blockIdx.x >> 1, kc = blockIdx.x & 1, nt = blockIdx.y;
  const int cnt = counts[e * CPAD];
  if (mt * 128 >= cnt) return;
  const int rem = min(128, cnt - mt * 128);
  const int* lst = list + e * TTOK + mt * 128;

  __shared__ __align__(16) char SM[18432];
  unsigned short* Sb = (unsigned short*)SM;

  const int tid = threadIdx.x;
  const int wave = tid >> 6, lane = tid & 63;
  const int srow = tid >> 2, cell = tid & 3;

  const int pr0 = lst[min(srow, rem - 1)];
  const int pr1 = lst[min(srow + 64, rem - 1)];
  const unsigned short* a0 = h + (size_t)pr0 * UDIM + kc * KCH + cell * 8;
  const unsigned short* a1 = h + (size_t)pr1 * UDIM + kc * KCH + cell * 8;
  const float* bw0 = wd + ((size_t)e * DDIM + nt * 128 + srow) * UDIM + kc * KCH + cell * 8;
  const float* bw1 = bw0 + (size_t)64 * UDIM;

  const int wm = wave >> 1, wn = wave & 1;
  const int lane15 = lane & 15, quad = lane >> 4;
  const int abyte = (wm * 64 + lane15) * 64 + quad * 16;
  const int bbyte = 8192 + (wn * 64 + lane15) * 64 + quad * 16;

  float4v p00 = *(const float4v*)(bw0);
  float4v p01 = *(const float4v*)(bw0 + 4);
  float4v p10 = *(const float4v*)(bw1);
  float4v p11 = *(const float4v*)(bw1 + 4);

  float4v acc[4][4];
#pragma unroll
  for (int i = 0; i < 4; i++)
#pragma unroll
    for (int j = 0; j < 4; j++) acc[i][j] = (float4v){0.f, 0.f, 0.f, 0.f};

  for (int k0 = 0; k0 < KCH; k0 += 32) {
    load_lds16(a0 + k0, SM + tid * 16);
    load_lds16(a1 + k0, SM + 4096 + tid * 16);
    short8 bv0 = cvt8(p00, p01);
    short8 bv1 = cvt8(p10, p11);
    if (k0 + 32 < KCH) {
      p00 = *(const float4v*)(bw0 + k0 + 32);
      p01 = *(const float4v*)(bw0 + k0 + 36);
      p10 = *(const float4v*)(bw1 + k0 + 32);
      p11 = *(const float4v*)(bw1 + k0 + 36);
    }
    *(short8*)(SM + 8192 + tid * 16) = bv0;
    *(short8*)(SM + 12288 + tid * 16) = bv1;
    __syncthreads();
    short8 af[4], bfr[4];
#pragma unroll
    for (int mi = 0; mi < 4; mi++) af[mi] = *(const short8*)(SM + abyte + mi * 1024);
#pragma unroll
    for (int ni = 0; ni < 4; ni++) bfr[ni] = *(const short8*)(SM + bbyte + ni * 1024);
#pragma unroll
    for (int mi = 0; mi < 4; mi++)
#pragma unroll
      for (int ni = 0; ni < 4; ni++)
        acc[mi][ni] = __builtin_amdgcn_mfma_f32_16x16x32_bf16(af[mi], bfr[ni], acc[mi][ni], 0, 0, 0);
    __syncthreads();
  }

  const int row = tid >> 1, seg = tid & 1;
  const int opair = (row < rem) ? lst[row] : -1;
#pragma unroll
  for (int hh = 0; hh < 2; hh++) {
    if (wn == hh) {
#pragma unroll
      for (int mi = 0; mi < 4; mi++)
#pragma unroll
        for (int r = 0; r < 4; r++) {
          const int rl = wm * 64 + mi * 16 + quad * 4 + r;
#pragma unroll
          for (int ni = 0; ni < 4; ni++)
            Sb[rl * EPAD + ni * 16 + lane15] = f2bf(acc[mi][ni][r]);
        }
    }
    __syncthreads();
    if (opair >= 0) {
      unsigned short* dst = part + ((size_t)kc * NPAIR + opair) * DDIM + nt * 128 + hh * 64 + seg * 32;
      const unsigned short* src = Sb + row * EPAD + seg * 32;
#pragma unroll
      for (int c = 0; c < 4; c++) *(ushort8*)(dst + c * 8) = *(const ushort8*)(src + c * 8);
    }
    __syncthreads();
  }
}

// ======== fallback stage_down (atomic accumulate into out; used when ws lacks part buffer) ========
__global__ __launch_bounds__(256, 3) void stage_down_k(
    const unsigned short* __restrict__ h, const float* __restrict__ wd,
    const float* __restrict__ bdn, const float* __restrict__ wpair,
    const int* __restrict__ counts, const int* __restrict__ list,
    float* __restrict__ out) {
  const int e = blockIdx.z, mt = blockIdx.y >> 1, kc = blockIdx.y & 1, nt = blockIdx.x;
  const int cnt = counts[e * CPAD];
  if (mt * 128 >= cnt) return;
  const int rem = min(128, cnt - mt * 128);
  const int* lst = list + e * TTOK + mt * 128;

  __shared__ __align__(16) char SM[18432];

  const int tid = threadIdx.x;
  const int wave = tid >> 6, lane = tid & 63;
  const int srow = tid >> 2, cell = tid & 3;

  const int pr0 = lst[min(srow, rem - 1)];
  const int pr1 = lst[min(srow + 64, rem - 1)];
  const unsigned short* a0 = h + (size_t)pr0 * UDIM + kc * KCH + cell * 8;
  const unsigned short* a1 = h + (size_t)pr1 * UDIM + kc * KCH + cell * 8;
  const float* bw0 = wd + ((size_t)e * DDIM + nt * 128 + srow) * UDIM + kc * KCH + cell * 8;
  const float* bw1 = bw0 + (size_t)64 * UDIM;

  const int wm = wave >> 1, wn = wave & 1;
  const int lane15 = lane & 15, quad = lane >> 4;
  const int abyte = (wm * 64 + lane15) * 64 + quad * 16;
  const int bbyte = 8192 + (wn * 64 + lane15) * 64 + quad * 16;

  float4v p00 = *(const float4v*)(bw0);
  float4v p01 = *(const float4v*)(bw0 + 4);
  float4v p10 = *(const float4v*)(bw1);
  float4v p11 = *(const float4v*)(bw1 + 4);

  float4v acc[4][4];
#pragma unroll
  for (int i = 0; i < 4; i++)
#pragma unroll
    for (int j = 0; j < 4; j++) acc[i][j] = (float4v){0.f, 0.f, 0.f, 0.f};

  for (int k0 = 0; k0 < KCH; k0 += 32) {
    load_lds16(a0 + k0, SM + tid * 16);
    load_lds16(a1 + k0, SM + 4096 + tid * 16);
    short8 bv0 = cvt8(p00, p01);
    short8 bv1 = cvt8(p10, p11);
    if (k0 + 32 < KCH) {
      p00 = *(const float4v*)(bw0 + k0 + 32);
      p01 = *(const float4v*)(bw0 + k0 + 36);
      p10 = *(const float4v*)(bw1 + k0 + 32);
      p11 = *(const float4v*)(bw1 + k0 + 36);
    }
    *(short8*)(SM + 8192 + tid * 16) = bv0;
    *(short8*)(SM + 12288 + tid * 16) = bv1;
    __syncthreads();
    short8 af[4], bfr[4];
#pragma unroll
    for (int mi = 0; mi < 4; mi++) af[mi] = *(const short8*)(SM + abyte + mi * 1024);
#pragma unroll
    for (int ni = 0; ni < 4; ni++) bfr[ni] = *(const short8*)(SM + bbyte + ni * 1024);
#pragma unroll
    for (int mi = 0; mi < 4; mi++)
#pragma unroll
      for (int ni = 0; ni < 4; ni++)
        acc[mi][ni] = __builtin_amdgcn_mfma_f32_16x16x32_bf16(af[mi], bfr[ni], acc[mi][ni], 0, 0, 0);
    __syncthreads();
  }

  const int dcol0 = nt * 128 + wn * 64;
  float bias[4];
#pragma unroll
  for (int ni = 0; ni < 4; ni++)
    bias[ni] = (kc == 0) ? bdn[e * DDIM + dcol0 + ni * 16 + lane15] : 0.0f;
#pragma unroll
  for (int mi = 0; mi < 4; mi++)
#pragma unroll
    for (int r = 0; r < 4; r++) {
      const int mrow = wm * 64 + mi * 16 + quad * 4 + r;
      if (mrow < rem) {
        const int pair = lst[mrow];
        const float w = wpair[pair];
        float* orow = out + (size_t)(pair >> 1) * DDIM;
#pragma unroll
        for (int ni = 0; ni < 4; ni++)
          atomicAdd(&orow[dcol0 + ni * 16 + lane15], w * (acc[mi][ni][r] + bias[ni]));
      }
    }
}

// ---------------- combine: out[t,d] = sum_j w_j * (bdn[e_j,d] + sum_kc part[kc,2t+j,d]) ----------------
__global__ void combine_kernel(const unsigned short* __restrict__ part,
                               const float* __restrict__ bdn,
                               const float* __restrict__ wpair,
                               const int* __restrict__ epair,
                               float* __restrict__ out) {
  const int idx = blockIdx.x * 256 + threadIdx.x;
  const int t = idx >> 7, c8 = (idx & 127) * 8;
  const size_t kstride = (size_t)NPAIR * DDIM;
  const unsigned short* pa = part + (size_t)(2 * t) * DDIM + c8;
  float s0[8], s1[8];
#pragma unroll
  for (int j = 0; j < 8; j++) { s0[j] = 0.f; s1[j] = 0.f; }
#pragma unroll
  for (int kc = 0; kc < KSPLIT; kc++) {
    ushort8 a = *(const ushort8*)(pa + kc * kstride);
    ushort8 b = *(const ushort8*)(pa + kc * kstride + DDIM);
#pragma unroll
    for (int j = 0; j < 8; j++) { s0[j] += bf2f(a[j]); s1[j] += bf2f(b[j]); }
  }
  const float w0 = wpair[2 * t], w1 = wpair[2 * t + 1];
  const int e0 = epair[2 * t], e1 = epair[2 * t + 1];
  const float* b0 = bdn + e0 * DDIM + c8;
  const float* b1 = bdn + e1 * DDIM + c8;
  float4v o[2];
#pragma unroll
  for (int half = 0; half < 2; half++)
#pragma unroll
    for (int j = 0; j < 4; j++) {
      const int jj = half * 4 + j;
      o[half][j] = w0 * (s0[jj] + b0[jj]) + w1 * (s1[jj] + b1[jj]);
    }
  float4v* dst = (float4v*)(out + (size_t)t * DDIM + c8);
  dst[0] = o[0]; dst[1] = o[1];
}

__global__ void zero_out_k(float4v* __restrict__ out) {
  const int tid = blockIdx.x * blockDim.x + threadIdx.x;
  const int O4 = TTOK * DDIM / 4;
  const int stride = gridDim.x * blockDim.x;
  for (int i = tid; i < O4; i += stride) out[i] = (float4v){0.f, 0.f, 0.f, 0.f};
}

extern "C" void kernel_launch(void* const* d_in, const int* in_sizes, int n_in,
                              void* d_out, int out_size, void* d_ws, size_t ws_size,
                              hipStream_t stream) {
  (void)in_sizes; (void)n_in; (void)out_size;
  const float* x        = (const float*)d_in[0];
  const float* w_router = (const float*)d_in[1];
  const float* w_up     = (const float*)d_in[2];
  const float* b_up     = (const float*)d_in[3];
  const float* w_down   = (const float*)d_in[4];
  const float* b_down   = (const float*)d_in[5];
  float* out = (float*)d_out;

  char* ws = (char*)d_ws;
  size_t off = 0;
  auto take = [&](size_t b) { size_t o = off; off = (off + b + 255) & ~(size_t)255; return o; };
  unsigned short* h  = (unsigned short*)(ws + take((size_t)NPAIR * UDIM * 2));   // 64 MiB
  unsigned short* xb = (unsigned short*)(ws + take((size_t)TTOK * DDIM * 2));    // 8 MiB
  int* counts        = (int*)(ws + take(NEXP * CPAD * 4));
  int* list          = (int*)(ws + take((size_t)NEXP * TTOK * 4));
  float* wpair       = (float*)(ws + take((size_t)NPAIR * 4));
  int* epair         = (int*)(ws + take((size_t)NPAIR * 4));
  size_t part_off    = take((size_t)KSPLIT * NPAIR * DDIM * 2);                  // 32 MiB
  const bool partmode = ws_size >= off;

  hipMemsetAsync(counts, 0, NEXP * CPAD * 4, stream);

  router_kernel<<<TTOK / RTOK, 256, 0, stream>>>(x, w_router, counts, list, wpair, epair, xb);
  stage_up_rs<<<dim3(UDIM / 128, 32, NEXP), 256, 0, stream>>>(xb, w_up, b_up, counts, list, h);

  if (partmode) {
    unsigned short* part = (unsigned short*)(ws + part_off);
    stage_down_rs<<<dim3(32 * KSPLIT, DDIM / 128, NEXP), 256, 0, stream>>>(
        h, w_down, counts, list, part);
    combine_kernel<<<TTOK * DDIM / 8 / 256, 256, 0, stream>>>(part, b_down, wpair, epair, out);
  } else {
    zero_out_k<<<1024, 256, 0, stream>>>((float4v*)out);
    stage_down_k<<<dim3(DDIM / 128, 32 * KSPLIT, NEXP), 256, 0, stream>>>(
        h, w_down, b_down, wpair, counts, list, out);
  }
}

// Round 5
// 571.132 us; speedup vs baseline: 1.1086x; 1.1086x over previous
//
#include <hip/hip_runtime.h>
#include <hip/hip_bf16.h>
#include <stdint.h>
#include <math.h>

// Problem constants (B=2,S=2048 -> T=4096 tokens), D=1024, U=4096, E=8, K=2
#define TTOK 4096
#define DDIM 1024
#define UDIM 4096
#define NEXP 8
#define KSPLIT 2            // split-K chunks for stage_down (K=4096 -> 2x2048)
#define KCH   (UDIM / KSPLIT)
#define NPAIR (TTOK * 2)
#define EPAD 72             // epilogue LDS bounce row stride (shorts)
#define CPAD 32             // counter padding (ints) -> one counter per 128B line
#define RBLK 128            // router blocks in prep (32 tokens each)
#define CBLK 2048           // conversion blocks in prep (both tensors)
#define RTOK 16             // tokens per router block (fallback router)

using float4v = __attribute__((ext_vector_type(4))) float;
using short8  = __attribute__((ext_vector_type(8))) short;
using ushort8 = __attribute__((ext_vector_type(8))) unsigned short;
using ushort4v = __attribute__((ext_vector_type(4))) unsigned short;

__device__ __forceinline__ unsigned short f2bf(float f) {
  union { float f; unsigned u; } v; v.f = f;
  unsigned r = v.u + 0x7FFFu + ((v.u >> 16) & 1u);  // RNE
  return (unsigned short)(r >> 16);
}
__device__ __forceinline__ float bf2f(unsigned short u) {
  union { unsigned u; float f; } v; v.u = ((unsigned)u) << 16;
  return v.f;
}
__device__ __forceinline__ void load_lds16(const void* g, void* l) {
  __builtin_amdgcn_global_load_lds(
      (const __attribute__((address_space(1))) unsigned int*)g,
      (__attribute__((address_space(3))) unsigned int*)l, 16, 0, 0);
}
// non-temporal streaming helpers: weight conversion data is single-use on the write
// side and must NOT evict h/xb/part from L3.
__device__ __forceinline__ float4v ntld4(const float* p) {
  return __builtin_nontemporal_load((const float4v*)p);
}
__device__ __forceinline__ void ntst8(unsigned short* p, const short8 v) {
  __builtin_nontemporal_store(v, (short8*)p);
}
// 8 fp32 -> 8 bf16 (RNE), packed
__device__ __forceinline__ short8 cvt8(const float4v a, const float4v b) {
  union { __hip_bfloat162 h[4]; short8 s; } u;
  u.h[0] = __float22bfloat162_rn(make_float2(a[0], a[1]));
  u.h[1] = __float22bfloat162_rn(make_float2(a[2], a[3]));
  u.h[2] = __float22bfloat162_rn(make_float2(b[0], b[1]));
  u.h[3] = __float22bfloat162_rn(make_float2(b[2], b[3]));
  return u.s;
}
// tanh-form gelu: v * sigmoid(2*0.797885*(v+0.044715 v^3)); NaN-safe at +-inf of exp
__device__ __forceinline__ float gelu_f(float v) {
  float u = v * (0.7978845608f + 0.0356774081f * v * v);
  float ex = __expf(2.0f * u);
  return v * (1.0f - 1.0f / (1.0f + ex));
}

// ---------------- prep: weight fp32->bf16 (blocks 0..CBLK-1, 1-deep prefetch, nt)
// + router via block-aggregated counting sort (last RBLK blocks, 32 tokens each) ----------------
__global__ void prep_kernel(const float* __restrict__ x, const float* __restrict__ wr,
                            int* __restrict__ counts, int* __restrict__ list,
                            float* __restrict__ wpair, int* __restrict__ epair,
                            unsigned short* __restrict__ xb,
                            const float* __restrict__ wu, const float* __restrict__ wd,
                            unsigned short* __restrict__ wub, unsigned short* __restrict__ wdb) {
  __shared__ int sE0[32], sE1[32];
  const int bid = blockIdx.x;
  const int tid = threadIdx.x;

  if (bid < CBLK) {
    // ---- conversion: 4096 groups-of-8 per block; 16 iters, 1-deep prefetch ----
    const float* s; unsigned short* d; size_t i0;
    if (bid < CBLK / 2) { s = wu; d = wub; i0 = (size_t)bid * 4096; }
    else                { s = wd; d = wdb; i0 = (size_t)(bid - CBLK / 2) * 4096; }
    const float* sp = s + (i0 + tid) * 8;
    unsigned short* dp = d + (i0 + tid) * 8;
    float4v p0 = ntld4(sp), p1 = ntld4(sp + 4);
#pragma unroll
    for (int it = 0; it < 16; it++) {
      float4v c0 = p0, c1 = p1;
      if (it + 1 < 16) {
        p0 = ntld4(sp + (size_t)(it + 1) * 2048);
        p1 = ntld4(sp + (size_t)(it + 1) * 2048 + 4);
      }
      ntst8(dp + (size_t)it * 2048, cvt8(c0, c1));
    }
    return;
  }

  // ---- router: 32 tokens/block, 8 tokens per wave ----
  const int rb = bid - CBLK;
  const int wave = tid >> 6, lane = tid & 63;
#pragma unroll 1
  for (int j = 0; j < 8; j++) {
    const int slot = wave * 8 + j;
    const int t = rb * 32 + slot;
    float acc[NEXP];
#pragma unroll
    for (int e = 0; e < NEXP; e++) acc[e] = 0.0f;
    const float* xr = x + (size_t)t * DDIM;
    unsigned short* xbr = xb + (size_t)t * DDIM;
#pragma unroll
    for (int it = 0; it < 4; it++) {
      const int d = it * 256 + lane * 4;
      float4v xv = *(const float4v*)(xr + d);
      ushort4v xo;
#pragma unroll
      for (int c = 0; c < 4; c++) xo[c] = f2bf(xv[c]);
      *(ushort4v*)(xbr + d) = xo;
#pragma unroll
      for (int e = 0; e < NEXP; e++) {
        float4v wv = *(const float4v*)(wr + e * DDIM + d);
        acc[e] += xv[0] * wv[0] + xv[1] * wv[1] + xv[2] * wv[2] + xv[3] * wv[3];
      }
    }
#pragma unroll
    for (int e = 0; e < NEXP; e++) {
#pragma unroll
      for (int off = 32; off > 0; off >>= 1) acc[e] += __shfl_xor(acc[e], off, 64);
    }
    if (lane == 0) {
      int e0 = 0; float l0 = acc[0];
      for (int e = 1; e < NEXP; e++) if (acc[e] > l0) { l0 = acc[e]; e0 = e; }
      int e1 = -1; float l1 = -3.4e38f;
      for (int e = 0; e < NEXP; e++) if (e != e0 && acc[e] > l1) { l1 = acc[e]; e1 = e; }
      float s1 = expf(l1 - l0);
      float inv = 1.0f / (1.0f + s1);
      wpair[2 * t] = inv;          epair[2 * t] = e0;
      wpair[2 * t + 1] = s1 * inv; epair[2 * t + 1] = e1;
      sE0[slot] = e0;  sE1[slot] = e1;
    }
  }
  __syncthreads();
  if (tid < NEXP) {
    const int e = tid;
    int cnt = 0;
#pragma unroll
    for (int s = 0; s < 32; s++) cnt += (sE0[s] == e) + (sE1[s] == e);
    int r = atomicAdd(&counts[e * CPAD], cnt);
    int* le = list + e * TTOK;
#pragma unroll 1
    for (int s = 0; s < 32; s++) {
      const int p = 2 * (rb * 32 + s);
      if (sE0[s] == e) le[r++] = p;
      if (sE1[s] == e) le[r++] = p + 1;
    }
  }
}

// ======== bf16-weight stage A: h[pair,u] = gelu(x . Wup + bup). m97 K-loop.
// Grid x = e (8): XCD = bid%8 = e -> each XCD reads ONLY its expert's wub panel
// (8 MiB) and gathered xb rows; zero cross-XCD weight duplication. ========
__global__ __launch_bounds__(256, 4) void stage_up_b16(
    const unsigned short* __restrict__ xb, const unsigned short* __restrict__ wub,
    const float* __restrict__ bup, const int* __restrict__ counts,
    const int* __restrict__ list, unsigned short* __restrict__ h) {
  const int e = blockIdx.x, nt = blockIdx.y, mt = blockIdx.z;
  const int cnt = counts[e * CPAD];
  if (mt * 128 >= cnt) return;
  const int rem = min(128, cnt - mt * 128);
  const int* lst = list + e * TTOK + mt * 128;

  __shared__ __align__(16) char SM[18432];   // A bf16 8K | B bf16 8K; epilogue bounce 18K
  unsigned short* Sb = (unsigned short*)SM;

  const int tid = threadIdx.x;
  const int wave = tid >> 6, lane = tid & 63;
  const int srow = tid >> 2, cell = tid & 3;          // DMA: 4 thr/row (64B bf16 rows)

  const int tok0 = lst[min(srow, rem - 1)] >> 1;
  const int tok1 = lst[min(srow + 64, rem - 1)] >> 1;
  const unsigned short* a0 = xb + (size_t)tok0 * DDIM + cell * 8;
  const unsigned short* a1 = xb + (size_t)tok1 * DDIM + cell * 8;
  const unsigned short* b0 = wub + ((size_t)e * UDIM + nt * 128 + srow) * DDIM + cell * 8;
  const unsigned short* b1 = b0 + (size_t)64 * DDIM;

  const int wm = wave >> 1, wn = wave & 1;
  const int lane15 = lane & 15, quad = lane >> 4;
  const int abyte = (wm * 64 + lane15) * 64 + quad * 16;
  const int bbyte = 8192 + (wn * 64 + lane15) * 64 + quad * 16;

  float4v acc[4][4];
#pragma unroll
  for (int i = 0; i < 4; i++)
#pragma unroll
    for (int j = 0; j < 4; j++) acc[i][j] = (float4v){0.f, 0.f, 0.f, 0.f};

  for (int k0 = 0; k0 < DDIM; k0 += 32) {
    load_lds16(a0 + k0, SM + tid * 16);
    load_lds16(a1 + k0, SM + 4096 + tid * 16);
    load_lds16(b0 + k0, SM + 8192 + tid * 16);
    load_lds16(b1 + k0, SM + 12288 + tid * 16);
    __syncthreads();
    short8 af[4], bfr[4];
#pragma unroll
    for (int mi = 0; mi < 4; mi++) af[mi] = *(const short8*)(SM + abyte + mi * 1024);
#pragma unroll
    for (int ni = 0; ni < 4; ni++) bfr[ni] = *(const short8*)(SM + bbyte + ni * 1024);
#pragma unroll
    for (int mi = 0; mi < 4; mi++)
#pragma unroll
      for (int ni = 0; ni < 4; ni++)
        acc[mi][ni] = __builtin_amdgcn_mfma_f32_16x16x32_bf16(af[mi], bfr[ni], acc[mi][ni], 0, 0, 0);
    __syncthreads();
  }

  // epilogue: +bias, fast gelu -> bf16, LDS bounce, coalesced 16B stores
  const int ucol0 = nt * 128 + wn * 64;
  float bias[4];
#pragma unroll
  for (int ni = 0; ni < 4; ni++) bias[ni] = bup[e * UDIM + ucol0 + ni * 16 + lane15];
  const int row = tid >> 1, seg = tid & 1;
  const int opair = (row < rem) ? lst[row] : -1;
#pragma unroll
  for (int hh = 0; hh < 2; hh++) {
    if (wn == hh) {
#pragma unroll
      for (int mi = 0; mi < 4; mi++)
#pragma unroll
        for (int r = 0; r < 4; r++) {
          const int rl = wm * 64 + mi * 16 + quad * 4 + r;
#pragma unroll
          for (int ni = 0; ni < 4; ni++)
            Sb[rl * EPAD + ni * 16 + lane15] = f2bf(gelu_f(acc[mi][ni][r] + bias[ni]));
        }
    }
    __syncthreads();
    if (opair >= 0) {
      unsigned short* dst = h + (size_t)opair * UDIM + nt * 128 + hh * 64 + seg * 32;
      const unsigned short* src = Sb + row * EPAD + seg * 32;
#pragma unroll
      for (int c = 0; c < 4; c++) *(ushort8*)(dst + c * 8) = *(const ushort8*)(src + c * 8);
    }
    __syncthreads();
  }
}

// ======== bf16-weight stage B: partial[kc][pair] = h . Wdown (no bias/w).
// Grid x = e (8): XCD = e -> each XCD reads only its expert's h rows (~8 MiB)
// and wdb panel (8 MiB); no cross-XCD re-fetch of either operand. ========
__global__ __launch_bounds__(256, 4) void stage_down_b16(
    const unsigned short* __restrict__ h, const unsigned short* __restrict__ wdb,
    const int* __restrict__ counts, const int* __restrict__ list,
    unsigned short* __restrict__ part) {
  const int e = blockIdx.x, nt = blockIdx.y, mt = blockIdx.z >> 1, kc = blockIdx.z & 1;
  const int cnt = counts[e * CPAD];
  if (mt * 128 >= cnt) return;
  const int rem = min(128, cnt - mt * 128);
  const int* lst = list + e * TTOK + mt * 128;

  __shared__ __align__(16) char SM[18432];
  unsigned short* Sb = (unsigned short*)SM;

  const int tid = threadIdx.x;
  const int wave = tid >> 6, lane = tid & 63;
  const int srow = tid >> 2, cell = tid & 3;

  const int pr0 = lst[min(srow, rem - 1)];
  const int pr1 = lst[min(srow + 64, rem - 1)];
  const unsigned short* a0 = h + (size_t)pr0 * UDIM + kc * KCH + cell * 8;
  const unsigned short* a1 = h + (size_t)pr1 * UDIM + kc * KCH + cell * 8;
  const unsigned short* b0 = wdb + ((size_t)e * DDIM + nt * 128 + srow) * UDIM + kc * KCH + cell * 8;
  const unsigned short* b1 = b0 + (size_t)64 * UDIM;

  const int wm = wave >> 1, wn = wave & 1;
  const int lane15 = lane & 15, quad = lane >> 4;
  const int abyte = (wm * 64 + lane15) * 64 + quad * 16;
  const int bbyte = 8192 + (wn * 64 + lane15) * 64 + quad * 16;

  float4v acc[4][4];
#pragma unroll
  for (int i = 0; i < 4; i++)
#pragma unroll
    for (int j = 0; j < 4; j++) acc[i][j] = (float4v){0.f, 0.f, 0.f, 0.f};

  for (int k0 = 0; k0 < KCH; k0 += 32) {
    load_lds16(a0 + k0, SM + tid * 16);
    load_lds16(a1 + k0, SM + 4096 + tid * 16);
    load_lds16(b0 + k0, SM + 8192 + tid * 16);
    load_lds16(b1 + k0, SM + 12288 + tid * 16);
    __syncthreads();
    short8 af[4], bfr[4];
#pragma unroll
    for (int mi = 0; mi < 4; mi++) af[mi] = *(const short8*)(SM + abyte + mi * 1024);
#pragma unroll
    for (int ni = 0; ni < 4; ni++) bfr[ni] = *(const short8*)(SM + bbyte + ni * 1024);
#pragma unroll
    for (int mi = 0; mi < 4; mi++)
#pragma unroll
      for (int ni = 0; ni < 4; ni++)
        acc[mi][ni] = __builtin_amdgcn_mfma_f32_16x16x32_bf16(af[mi], bfr[ni], acc[mi][ni], 0, 0, 0);
    __syncthreads();
  }

  const int row = tid >> 1, seg = tid & 1;
  const int opair = (row < rem) ? lst[row] : -1;
#pragma unroll
  for (int hh = 0; hh < 2; hh++) {
    if (wn == hh) {
#pragma unroll
      for (int mi = 0; mi < 4; mi++)
#pragma unroll
        for (int r = 0; r < 4; r++) {
          const int rl = wm * 64 + mi * 16 + quad * 4 + r;
#pragma unroll
          for (int ni = 0; ni < 4; ni++)
            Sb[rl * EPAD + ni * 16 + lane15] = f2bf(acc[mi][ni][r]);
        }
    }
    __syncthreads();
    if (opair >= 0) {
      unsigned short* dst = part + ((size_t)kc * NPAIR + opair) * DDIM + nt * 128 + hh * 64 + seg * 32;
      const unsigned short* src = Sb + row * EPAD + seg * 32;
#pragma unroll
      for (int c = 0; c < 4; c++) *(ushort8*)(dst + c * 8) = *(const ushort8*)(src + c * 8);
    }
    __syncthreads();
  }
}

// ======== fallback tier: router + fp32-weight reg-staged stages (R4-verified) ========
__global__ void router_kernel(const float* __restrict__ x,
                              const float* __restrict__ wr,
                              int* __restrict__ counts, int* __restrict__ list,
                              float* __restrict__ wpair, int* __restrict__ epair,
                              unsigned short* __restrict__ xb) {
  __shared__ int sE0[RTOK], sE1[RTOK];
  const int bid = blockIdx.x;
  const int tid = threadIdx.x;
  const int wave = tid >> 6, lane = tid & 63;
#pragma unroll 1
  for (int j = 0; j < RTOK / 4; j++) {
    const int slot = wave * (RTOK / 4) + j;
    const int t = bid * RTOK + slot;
    float acc[NEXP];
#pragma unroll
    for (int e = 0; e < NEXP; e++) acc[e] = 0.0f;
    const float* xr = x + (size_t)t * DDIM;
    unsigned short* xbr = xb + (size_t)t * DDIM;
#pragma unroll
    for (int it = 0; it < 4; it++) {
      const int d = it * 256 + lane * 4;
      float4v xv = *(const float4v*)(xr + d);
      ushort4v xo;
#pragma unroll
      for (int c = 0; c < 4; c++) xo[c] = f2bf(xv[c]);
      *(ushort4v*)(xbr + d) = xo;
#pragma unroll
      for (int e = 0; e < NEXP; e++) {
        float4v wv = *(const float4v*)(wr + e * DDIM + d);
        acc[e] += xv[0] * wv[0] + xv[1] * wv[1] + xv[2] * wv[2] + xv[3] * wv[3];
      }
    }
#pragma unroll
    for (int e = 0; e < NEXP; e++) {
#pragma unroll
      for (int off = 32; off > 0; off >>= 1) acc[e] += __shfl_xor(acc[e], off, 64);
    }
    if (lane == 0) {
      int e0 = 0; float l0 = acc[0];
      for (int e = 1; e < NEXP; e++) if (acc[e] > l0) { l0 = acc[e]; e0 = e; }
      int e1 = -1; float l1 = -3.4e38f;
      for (int e = 0; e < NEXP; e++) if (e != e0 && acc[e] > l1) { l1 = acc[e]; e1 = e; }
      float s1 = expf(l1 - l0);
      float inv = 1.0f / (1.0f + s1);
      wpair[2 * t] = inv;          epair[2 * t] = e0;
      wpair[2 * t + 1] = s1 * inv; epair[2 * t + 1] = e1;
      sE0[slot] = e0;  sE1[slot] = e1;
    }
  }
  __syncthreads();
  if (tid < NEXP) {
    const int e = tid;
    int cnt = 0;
#pragma unroll
    for (int s = 0; s < RTOK; s++) cnt += (sE0[s] == e) + (sE1[s] == e);
    int r = atomicAdd(&counts[e * CPAD], cnt);
    int* le = list + e * TTOK;
#pragma unroll 1
    for (int s = 0; s < RTOK; s++) {
      const int p = 2 * (bid * RTOK + s);
      if (sE0[s] == e) le[r++] = p;
      if (sE1[s] == e) le[r++] = p + 1;
    }
  }
}

__global__ __launch_bounds__(256, 4) void stage_up_rs(
    const unsigned short* __restrict__ xb, const float* __restrict__ wu,
    const float* __restrict__ bup, const int* __restrict__ counts,
    const int* __restrict__ list, unsigned short* __restrict__ h) {
  const int e = blockIdx.z, mt = blockIdx.y, nt = blockIdx.x;
  const int cnt = counts[e * CPAD];
  if (mt * 128 >= cnt) return;
  const int rem = min(128, cnt - mt * 128);
  const int* lst = list + e * TTOK + mt * 128;

  __shared__ __align__(16) char SM[18432];
  unsigned short* Sb = (unsigned short*)SM;

  const int tid = threadIdx.x;
  const int wave = tid >> 6, lane = tid & 63;
  const int srow = tid >> 2, cell = tid & 3;

  const int tok0 = lst[min(srow, rem - 1)] >> 1;
  const int tok1 = lst[min(srow + 64, rem - 1)] >> 1;
  const unsigned short* a0 = xb + (size_t)tok0 * DDIM + cell * 8;
  const unsigned short* a1 = xb + (size_t)tok1 * DDIM + cell * 8;
  const float* bw0 = wu + ((size_t)e * UDIM + nt * 128 + srow) * DDIM + cell * 8;
  const float* bw1 = bw0 + (size_t)64 * DDIM;

  const int wm = wave >> 1, wn = wave & 1;
  const int lane15 = lane & 15, quad = lane >> 4;
  const int abyte = (wm * 64 + lane15) * 64 + quad * 16;
  const int bbyte = 8192 + (wn * 64 + lane15) * 64 + quad * 16;

  float4v p00 = *(const float4v*)(bw0);
  float4v p01 = *(const float4v*)(bw0 + 4);
  float4v p10 = *(const float4v*)(bw1);
  float4v p11 = *(const float4v*)(bw1 + 4);

  float4v acc[4][4];
#pragma unroll
  for (int i = 0; i < 4; i++)
#pragma unroll
    for (int j = 0; j < 4; j++) acc[i][j] = (float4v){0.f, 0.f, 0.f, 0.f};

  for (int k0 = 0; k0 < DDIM; k0 += 32) {
    load_lds16(a0 + k0, SM + tid * 16);
    load_lds16(a1 + k0, SM + 4096 + tid * 16);
    short8 bv0 = cvt8(p00, p01);
    short8 bv1 = cvt8(p10, p11);
    if (k0 + 32 < DDIM) {
      p00 = *(const float4v*)(bw0 + k0 + 32);
      p01 = *(const float4v*)(bw0 + k0 + 36);
      p10 = *(const float4v*)(bw1 + k0 + 32);
      p11 = *(const float4v*)(bw1 + k0 + 36);
    }
    *(short8*)(SM + 8192 + tid * 16) = bv0;
    *(short8*)(SM + 12288 + tid * 16) = bv1;
    __syncthreads();
    short8 af[4], bfr[4];
#pragma unroll
    for (int mi = 0; mi < 4; mi++) af[mi] = *(const short8*)(SM + abyte + mi * 1024);
#pragma unroll
    for (int ni = 0; ni < 4; ni++) bfr[ni] = *(const short8*)(SM + bbyte + ni * 1024);
#pragma unroll
    for (int mi = 0; mi < 4; mi++)
#pragma unroll
      for (int ni = 0; ni < 4; ni++)
        acc[mi][ni] = __builtin_amdgcn_mfma_f32_16x16x32_bf16(af[mi], bfr[ni], acc[mi][ni], 0, 0, 0);
    __syncthreads();
  }

  const int ucol0 = nt * 128 + wn * 64;
  float bias[4];
#pragma unroll
  for (int ni = 0; ni < 4; ni++) bias[ni] = bup[e * UDIM + ucol0 + ni * 16 + lane15];
  const int row = tid >> 1, seg = tid & 1;
  const int opair = (row < rem) ? lst[row] : -1;
#pragma unroll
  for (int hh = 0; hh < 2; hh++) {
    if (wn == hh) {
#pragma unroll
      for (int mi = 0; mi < 4; mi++)
#pragma unroll
        for (int r = 0; r < 4; r++) {
          const int rl = wm * 64 + mi * 16 + quad * 4 + r;
#pragma unroll
          for (int ni = 0; ni < 4; ni++)
            Sb[rl * EPAD + ni * 16 + lane15] = f2bf(gelu_f(acc[mi][ni][r] + bias[ni]));
        }
    }
    __syncthreads();
    if (opair >= 0) {
      unsigned short* dst = h + (size_t)opair * UDIM + nt * 128 + hh * 64 + seg * 32;
      const unsigned short* src = Sb + row * EPAD + seg * 32;
#pragma unroll
      for (int c = 0; c < 4; c++) *(ushort8*)(dst + c * 8) = *(const ushort8*)(src + c * 8);
    }
    __syncthreads();
  }
}

__global__ __launch_bounds__(256, 4) void stage_down_rs(
    const unsigned short* __restrict__ h, const float* __restrict__ wd,
    const int* __restrict__ counts, const int* __restrict__ list,
    unsigned short* __restrict__ part) {
  const int e = blockIdx.z, mt = blockIdx.x >> 1, kc = blockIdx.x & 1, nt = blockIdx.y;
  const int cnt = counts[e * CPAD];
  if (mt * 128 >= cnt) return;
  const int rem = min(128, cnt - mt * 128);
  const int* lst = list + e * TTOK + mt * 128;

  __shared__ __align__(16) char SM[18432];
  unsigned short* Sb = (unsigned short*)SM;

  const int tid = threadIdx.x;
  const int wave = tid >> 6, lane = tid & 63;
  const int srow = tid >> 2, cell = tid & 3;

  const int pr0 = lst[min(srow, rem - 1)];
  const int pr1 = lst[min(srow + 64, rem - 1)];
  const unsigned short* a0 = h + (size_t)pr0 * UDIM + kc * KCH + cell * 8;
  const unsigned short* a1 = h + (size_t)pr1 * UDIM + kc * KCH + cell * 8;
  const float* bw0 = wd + ((size_t)e * DDIM + nt * 128 + srow) * UDIM + kc * KCH + cell * 8;
  const float* bw1 = bw0 + (size_t)64 * UDIM;

  const int wm = wave >> 1, wn = wave & 1;
  const int lane15 = lane & 15, quad = lane >> 4;
  const int abyte = (wm * 64 + lane15) * 64 + quad * 16;
  const int bbyte = 8192 + (wn * 64 + lane15) * 64 + quad * 16;

  float4v p00 = *(const float4v*)(bw0);
  float4v p01 = *(const float4v*)(bw0 + 4);
  float4v p10 = *(const float4v*)(bw1);
  float4v p11 = *(const float4v*)(bw1 + 4);

  float4v acc[4][4];
#pragma unroll
  for (int i = 0; i < 4; i++)
#pragma unroll
    for (int j = 0; j < 4; j++) acc[i][j] = (float4v){0.f, 0.f, 0.f, 0.f};

  for (int k0 = 0; k0 < KCH; k0 += 32) {
    load_lds16(a0 + k0, SM + tid * 16);
    load_lds16(a1 + k0, SM + 4096 + tid * 16);
    short8 bv0 = cvt8(p00, p01);
    short8 bv1 = cvt8(p10, p11);
    if (k0 + 32 < KCH) {
      p00 = *(const float4v*)(bw0 + k0 + 32);
      p01 = *(const float4v*)(bw0 + k0 + 36);
      p10 = *(const float4v*)(bw1 + k0 + 32);
      p11 = *(const float4v*)(bw1 + k0 + 36);
    }
    *(short8*)(SM + 8192 + tid * 16) = bv0;
    *(short8*)(SM + 12288 + tid * 16) = bv1;
    __syncthreads();
    short8 af[4], bfr[4];
#pragma unroll
    for (int mi = 0; mi < 4; mi++) af[mi] = *(const short8*)(SM + abyte + mi * 1024);
#pragma unroll
    for (int ni = 0; ni < 4; ni++) bfr[ni] = *(const short8*)(SM + bbyte + ni * 1024);
#pragma unroll
    for (int mi = 0; mi < 4; mi++)
#pragma unroll
      for (int ni = 0; ni < 4; ni++)
        acc[mi][ni] = __builtin_amdgcn_mfma_f32_16x16x32_bf16(af[mi], bfr[ni], acc[mi][ni], 0, 0, 0);
    __syncthreads();
  }

  const int row = tid >> 1, seg = tid & 1;
  const int opair = (row < rem) ? lst[row] : -1;
#pragma unroll
  for (int hh = 0; hh < 2; hh++) {
    if (wn == hh) {
#pragma unroll
      for (int mi = 0; mi < 4; mi++)
#pragma unroll
        for (int r = 0; r < 4; r++) {
          const int rl = wm * 64 + mi * 16 + quad * 4 + r;
#pragma unroll
          for (int ni = 0; ni < 4; ni++)
            Sb[rl * EPAD + ni * 16 + lane15] = f2bf(acc[mi][ni][r]);
        }
    }
    __syncthreads();
    if (opair >= 0) {
      unsigned short* dst = part + ((size_t)kc * NPAIR + opair) * DDIM + nt * 128 + hh * 64 + seg * 32;
      const unsigned short* src = Sb + row * EPAD + seg * 32;
#pragma unroll
      for (int c = 0; c < 4; c++) *(ushort8*)(dst + c * 8) = *(const ushort8*)(src + c * 8);
    }
    __syncthreads();
  }
}

// ---------------- combine: out[t,d] = sum_j w_j * (bdn[e_j,d] + sum_kc part[kc,2t+j,d]) ----------------
__global__ void combine_kernel(const unsigned short* __restrict__ part,
                               const float* __restrict__ bdn,
                               const float* __restrict__ wpair,
                               const int* __restrict__ epair,
                               float* __restrict__ out) {
  const int idx = blockIdx.x * 256 + threadIdx.x;
  const int t = idx >> 7, c8 = (idx & 127) * 8;
  const size_t kstride = (size_t)NPAIR * DDIM;
  const unsigned short* pa = part + (size_t)(2 * t) * DDIM + c8;
  float s0[8], s1[8];
#pragma unroll
  for (int j = 0; j < 8; j++) { s0[j] = 0.f; s1[j] = 0.f; }
#pragma unroll
  for (int kc = 0; kc < KSPLIT; kc++) {
    ushort8 a = *(const ushort8*)(pa + kc * kstride);
    ushort8 b = *(const ushort8*)(pa + kc * kstride + DDIM);
#pragma unroll
    for (int j = 0; j < 8; j++) { s0[j] += bf2f(a[j]); s1[j] += bf2f(b[j]); }
  }
  const float w0 = wpair[2 * t], w1 = wpair[2 * t + 1];
  const int e0 = epair[2 * t], e1 = epair[2 * t + 1];
  const float* b0 = bdn + e0 * DDIM + c8;
  const float* b1 = bdn + e1 * DDIM + c8;
  float4v o[2];
#pragma unroll
  for (int half = 0; half < 2; half++)
#pragma unroll
    for (int j = 0; j < 4; j++) {
      const int jj = half * 4 + j;
      o[half][j] = w0 * (s0[jj] + b0[jj]) + w1 * (s1[jj] + b1[jj]);
    }
  float4v* dst = (float4v*)(out + (size_t)t * DDIM + c8);
  dst[0] = o[0]; dst[1] = o[1];
}

extern "C" void kernel_launch(void* const* d_in, const int* in_sizes, int n_in,
                              void* d_out, int out_size, void* d_ws, size_t ws_size,
                              hipStream_t stream) {
  (void)in_sizes; (void)n_in; (void)out_size;
  const float* x        = (const float*)d_in[0];
  const float* w_router = (const float*)d_in[1];
  const float* w_up     = (const float*)d_in[2];
  const float* b_up     = (const float*)d_in[3];
  const float* w_down   = (const float*)d_in[4];
  const float* b_down   = (const float*)d_in[5];
  float* out = (float*)d_out;

  char* ws = (char*)d_ws;
  size_t off = 0;
  auto take = [&](size_t b) { size_t o = off; off = (off + b + 255) & ~(size_t)255; return o; };
  unsigned short* h  = (unsigned short*)(ws + take((size_t)NPAIR * UDIM * 2));   // 64 MiB
  unsigned short* xb = (unsigned short*)(ws + take((size_t)TTOK * DDIM * 2));    // 8 MiB
  int* counts        = (int*)(ws + take(NEXP * CPAD * 4));
  int* list          = (int*)(ws + take((size_t)NEXP * TTOK * 4));
  float* wpair       = (float*)(ws + take((size_t)NPAIR * 4));
  int* epair         = (int*)(ws + take((size_t)NPAIR * 4));
  size_t part_off    = take((size_t)KSPLIT * NPAIR * DDIM * 2);                  // 32 MiB
  unsigned short* part = (unsigned short*)(ws + part_off);
  const bool partmode = ws_size >= off;
  size_t wub_off     = take((size_t)NEXP * UDIM * DDIM * 2);                     // 64 MiB
  size_t wdb_off     = take((size_t)NEXP * DDIM * UDIM * 2);                     // 64 MiB
  const bool bf16mode = ws_size >= off;

  hipMemsetAsync(counts, 0, NEXP * CPAD * 4, stream);

  if (bf16mode) {
    unsigned short* wub = (unsigned short*)(ws + wub_off);
    unsigned short* wdb = (unsigned short*)(ws + wdb_off);
    // conversions first (long pole), router in the tail
    prep_kernel<<<CBLK + RBLK, 256, 0, stream>>>(
        x, w_router, counts, list, wpair, epair, xb, w_up, w_down, wub, wdb);
    stage_up_b16<<<dim3(NEXP, UDIM / 128, 32), 256, 0, stream>>>(
        xb, wub, b_up, counts, list, h);
    stage_down_b16<<<dim3(NEXP, DDIM / 128, 32 * KSPLIT), 256, 0, stream>>>(
        h, wdb, counts, list, part);
    combine_kernel<<<TTOK * DDIM / 8 / 256, 256, 0, stream>>>(part, b_down, wpair, epair, out);
  } else if (partmode) {
    router_kernel<<<TTOK / RTOK, 256, 0, stream>>>(x, w_router, counts, list, wpair, epair, xb);
    stage_up_rs<<<dim3(UDIM / 128, 32, NEXP), 256, 0, stream>>>(xb, w_up, b_up, counts, list, h);
    stage_down_rs<<<dim3(32 * KSPLIT, DDIM / 128, NEXP), 256, 0, stream>>>(
        h, w_down, counts, list, part);
    combine_kernel<<<TTOK * DDIM / 8 / 256, 256, 0, stream>>>(part, b_down, wpair, epair, out);
  }
}